// Round 8
// baseline (105.022 us; speedup 1.0000x reference)
//
#include <hip/hip_runtime.h>
#include <math.h>

typedef unsigned long long u64;

constexpr int T_TOTAL = 16777216;          // 2^24
constexpr int TPB     = 256;               // 4 waves per block
constexpr int SEG     = 2048;              // elements per wave segment
constexpr int NSEG    = T_TOTAL / SEG;     // 8192 segments
constexpr int NBLK    = NSEG / 4;          // 2048 blocks
constexpr int ITERS   = SEG / 128;         // 16 iterations per wave
constexpr int BWRD    = 6;                 // ballot words per iteration
constexpr float THRESHOLD = 0.5f;

// ---------------- compressed path ----------------

// Pass 1: single streaming pass over on/off/u/e. Emits per-128-element
// ballot words (pos/neg net masks + over-threshold masks) and per-segment
// net sums. This is the ONLY kernel that touches the 384 MB.
__global__ void __launch_bounds__(TPB)
k_prep(const int2* __restrict__ on2, const int2* __restrict__ off2,
       const float4* __restrict__ u4, const float4* __restrict__ e4,
       u64* __restrict__ ballots, int* __restrict__ segsums) {
    const int lane = threadIdx.x & 63;
    const int wid  = threadIdx.x >> 6;
    const int seg  = blockIdx.x * 4 + wid;
    const int base = seg * (SEG / 2);          // int2 index == float4 index
    int ssum = 0;
    #pragma unroll 4
    for (int it = 0; it < ITERS; ++it) {
        const int idx = base + it * 64 + lane;
        int2   a  = on2[idx];
        int2   c  = off2[idx];
        float4 uv = u4[idx];
        float4 ev = e4[idx];
        u64 pos_e  = __ballot(a.x > c.x);                      // net=+1, evens
        u64 neg_e  = __ballot(c.x > a.x);                      // net=-1, evens
        u64 pos_o  = __ballot(a.y > c.y);                      // odds
        u64 neg_o  = __ballot(c.y > a.y);
        u64 over_e = __ballot(fabsf(ev.x - uv.x) > THRESHOLD); // col0 of elem 2i
        u64 over_o = __ballot(fabsf(ev.z - uv.z) > THRESHOLD); // col0 of elem 2i+1
        ssum += __popcll(pos_e) - __popcll(neg_e)
              + __popcll(pos_o) - __popcll(neg_o);
        u64 v = pos_e;
        v = (lane == 1) ? neg_e  : v;
        v = (lane == 2) ? pos_o  : v;
        v = (lane == 3) ? neg_o  : v;
        v = (lane == 4) ? over_e : v;
        v = (lane == 5) ? over_o : v;
        if (lane < BWRD) ballots[(size_t)(seg * ITERS + it) * BWRD + lane] = v;
    }
    if (lane == 0) segsums[seg] = ssum;
}

// Pass 2: exclusive scan of NSEG segment sums (single block, 32/thread)
__global__ void __launch_bounds__(TPB)
k_scan(int* __restrict__ segsums) {
    __shared__ int wsum[4];
    const int lane = threadIdx.x & 63;
    const int wid  = threadIdx.x >> 6;
    int vals[NSEG / TPB];
    const int base = threadIdx.x * (NSEG / TPB);
    int s = 0;
    #pragma unroll
    for (int i = 0; i < NSEG / TPB; i++) { vals[i] = segsums[base + i]; s += vals[i]; }
    int x = s;
    #pragma unroll
    for (int d = 1; d < 64; d <<= 1) {
        int y = __shfl_up(x, d);
        if (lane >= d) x += y;
    }
    if (lane == 63) wsum[wid] = x;
    __syncthreads();
    int wbase = 0;
    #pragma unroll
    for (int w = 0; w < 3; w++) if (w < wid) wbase += wsum[w];
    int ex = wbase + (x - s);
    #pragma unroll
    for (int i = 0; i < NSEG / TPB; i++) { int v = vals[i]; segsums[base + i] = ex; ex += v; }
}

// Pass 3: pure bit-math over the 6 MB ballot buffer (L2/L3-hot).
__global__ void __launch_bounds__(TPB)
k_count2(const u64* __restrict__ ballots, const int* __restrict__ segpre,
         int2* __restrict__ partials) {
    const int lane = threadIdx.x & 63;
    const int wid  = threadIdx.x >> 6;
    const int seg  = blockIdx.x * 4 + wid;
    const u64 le = (~0ull) >> (63 - lane);   // lanes 0..i
    const u64 lt = le >> 1;                  // lanes 0..i-1
    int basep = segpre[seg];
    int cover = 0, cact = 0;
    const ulonglong2* bb = (const ulonglong2*)(ballots + (size_t)seg * ITERS * BWRD);
    #pragma unroll 4
    for (int it = 0; it < ITERS; ++it) {
        ulonglong2 w0 = bb[it * 3 + 0];      // pos_e, neg_e
        ulonglong2 w1 = bb[it * 3 + 1];      // pos_o, neg_o
        ulonglong2 w2 = bb[it * 3 + 2];      // over_e, over_o
        const int de = __popcll(w0.x & le) - __popcll(w0.y & le);
        const int pe = basep + de + __popcll(w1.x & lt) - __popcll(w1.y & lt);
        const int po = basep + de + __popcll(w1.x & le) - __popcll(w1.y & le);
        basep += __popcll(w0.x) - __popcll(w0.y)
               + __popcll(w1.x) - __popcll(w1.y);
        const int a0 = pe > 0, a1 = po > 0;
        cact += a0 + a1;
        cover += (a0 & (int)((w2.x >> lane) & 1)) + (a1 & (int)((w2.y >> lane) & 1));
    }
    #pragma unroll
    for (int d = 32; d > 0; d >>= 1) {
        cover += __shfl_xor(cover, d);
        cact  += __shfl_xor(cact, d);
    }
    __shared__ int sc[4], sa[4];
    if (lane == 0) { sc[wid] = cover; sa[wid] = cact; }
    __syncthreads();
    if (threadIdx.x == 0)
        partials[blockIdx.x] = make_int2(sc[0] + sc[1] + sc[2] + sc[3],
                                         sa[0] + sa[1] + sa[2] + sa[3]);
}

// ---------------- fallback path (round-6 proven) ----------------
__global__ void __launch_bounds__(TPB)
k_segsums(const int2* __restrict__ on2, const int2* __restrict__ off2,
          int* __restrict__ segsums) {
    const int lane = threadIdx.x & 63;
    const int wid  = threadIdx.x >> 6;
    const int seg  = blockIdx.x * 4 + wid;
    const int base = seg * (SEG / 2);
    int s = 0;
    #pragma unroll
    for (int it = 0; it < ITERS; ++it) {
        int2 a = on2[base + it * 64 + lane];
        int2 c = off2[base + it * 64 + lane];
        s += a.x + a.y - c.x - c.y;
    }
    #pragma unroll
    for (int d = 32; d > 0; d >>= 1) s += __shfl_xor(s, d);
    if (lane == 0) segsums[seg] = s;
}

__global__ void __launch_bounds__(TPB)
k_count(const int2* __restrict__ on2, const int2* __restrict__ off2,
        const float4* __restrict__ u4, const float4* __restrict__ e4,
        const int* __restrict__ segpre, int2* __restrict__ partials) {
    const int lane = threadIdx.x & 63;
    const int wid  = threadIdx.x >> 6;
    const int seg  = blockIdx.x * 4 + wid;
    const int base = seg * (SEG / 2);
    const u64 le = (~0ull) >> (63 - lane);
    const u64 lt = le >> 1;
    int basep = segpre[seg];
    int cover = 0, cact = 0;
    #pragma unroll 4
    for (int it = 0; it < ITERS; ++it) {
        const int idx = base + it * 64 + lane;
        int2   a  = on2[idx];
        int2   c  = off2[idx];
        float4 uv = u4[idx];
        float4 ev = e4[idx];
        u64 be_on  = __ballot(a.x != 0);
        u64 bo_on  = __ballot(a.y != 0);
        u64 be_off = __ballot(c.x != 0);
        u64 bo_off = __ballot(c.y != 0);
        const int de = __popcll(be_on & le) - __popcll(be_off & le);
        const int pe = basep + de + __popcll(bo_on & lt) - __popcll(bo_off & lt);
        const int po = basep + de + __popcll(bo_on & le) - __popcll(bo_off & le);
        basep += __popcll(be_on) - __popcll(be_off)
               + __popcll(bo_on) - __popcll(bo_off);
        const int a0 = pe > 0, a1 = po > 0;
        cact += a0 + a1;
        if (a0 && fabsf(ev.x - uv.x) > THRESHOLD) cover++;
        if (a1 && fabsf(ev.z - uv.z) > THRESHOLD) cover++;
    }
    #pragma unroll
    for (int d = 32; d > 0; d >>= 1) {
        cover += __shfl_xor(cover, d);
        cact  += __shfl_xor(cact, d);
    }
    __shared__ int sc[4], sa[4];
    if (lane == 0) { sc[wid] = cover; sa[wid] = cact; }
    __syncthreads();
    if (threadIdx.x == 0)
        partials[blockIdx.x] = make_int2(sc[0] + sc[1] + sc[2] + sc[3],
                                         sa[0] + sa[1] + sa[2] + sa[3]);
}

// Pass 4: reduce block partials, divide
__global__ void __launch_bounds__(TPB)
k_final(const int2* __restrict__ partials, float* __restrict__ out) {
    const int lane = threadIdx.x & 63;
    const int wid  = threadIdx.x >> 6;
    int c = 0, a = 0;
    for (int i = threadIdx.x; i < NBLK; i += TPB) {
        int2 p = partials[i];
        c += p.x; a += p.y;
    }
    #pragma unroll
    for (int d = 32; d > 0; d >>= 1) {
        c += __shfl_xor(c, d);
        a += __shfl_xor(a, d);
    }
    __shared__ int sc[4], sa[4];
    if (lane == 0) { sc[wid] = c; sa[wid] = a; }
    __syncthreads();
    if (threadIdx.x == 0) {
        float ctot = (float)(sc[0] + sc[1] + sc[2] + sc[3]);
        float atot = (float)(sa[0] + sa[1] + sa[2] + sa[3]);
        out[0] = ctot / atot;
    }
}

extern "C" void kernel_launch(void* const* d_in, const int* in_sizes, int n_in,
                              void* d_out, int out_size, void* d_ws, size_t ws_size,
                              hipStream_t stream) {
    const float* u   = (const float*)d_in[0];
    const float* e   = (const float*)d_in[1];
    const int*   on  = (const int*)d_in[2];
    const int*   off = (const int*)d_in[3];

    int*  segsums  = (int*)d_ws;                        // 32 KB
    int2* partials = (int2*)(segsums + NSEG);           // 16 KB
    u64*  ballots  = (u64*)((char*)d_ws + 48 * 1024);   // 6 MB

    const size_t need = 48 * 1024 + (size_t)NSEG * ITERS * BWRD * sizeof(u64);

    if (ws_size >= need) {
        k_prep<<<NBLK, TPB, 0, stream>>>((const int2*)on, (const int2*)off,
                                         (const float4*)u, (const float4*)e,
                                         ballots, segsums);
        k_scan<<<1, TPB, 0, stream>>>(segsums);
        k_count2<<<NBLK, TPB, 0, stream>>>(ballots, segsums, partials);
    } else {
        k_segsums<<<NBLK, TPB, 0, stream>>>((const int2*)on, (const int2*)off, segsums);
        k_scan<<<1, TPB, 0, stream>>>(segsums);
        k_count<<<NBLK, TPB, 0, stream>>>((const int2*)on, (const int2*)off,
                                          (const float4*)u, (const float4*)e,
                                          segsums, partials);
    }
    k_final<<<1, TPB, 0, stream>>>(partials, (float*)d_out);
}

// Round 9
// 91.358 us; speedup vs baseline: 1.1496x; 1.1496x over previous
//
#include <hip/hip_runtime.h>
#include <math.h>

typedef unsigned long long u64;

constexpr int T_TOTAL = 16777216;          // 2^24
constexpr int TPB     = 256;               // 4 waves per block
constexpr int SEG     = 2048;              // elements per wave segment
constexpr int NSEG    = T_TOTAL / SEG;     // 8192 segments
constexpr int NBLK    = NSEG / 4;          // 2048 blocks
constexpr int ITERS   = SEG / 128;         // 16 iterations per wave
constexpr float THRESHOLD = 0.5f;

// Pass 1: per-segment net sums. Loads batched 4-deep (no cross-lane ops
// between loads, so the scheduler keeps 8 loads in flight).
__global__ void __launch_bounds__(TPB)
k_segsums(const int2* __restrict__ on2, const int2* __restrict__ off2,
          int* __restrict__ segsums) {
    const int lane = threadIdx.x & 63;
    const int wid  = threadIdx.x >> 6;
    const int seg  = blockIdx.x * 4 + wid;
    const int base = seg * (SEG / 2);          // int2 index
    int s = 0;
    #pragma unroll
    for (int g = 0; g < ITERS / 4; ++g) {
        const int i0 = base + g * 256 + lane;
        int2 a0 = on2[i0];       int2 a1 = on2[i0 + 64];
        int2 a2 = on2[i0 + 128]; int2 a3 = on2[i0 + 192];
        int2 c0 = off2[i0];       int2 c1 = off2[i0 + 64];
        int2 c2 = off2[i0 + 128]; int2 c3 = off2[i0 + 192];
        s += (a0.x + a0.y - c0.x - c0.y) + (a1.x + a1.y - c1.x - c1.y)
           + (a2.x + a2.y - c2.x - c2.y) + (a3.x + a3.y - c3.x - c3.y);
    }
    #pragma unroll
    for (int d = 32; d > 0; d >>= 1) s += __shfl_xor(s, d);
    if (lane == 0) segsums[seg] = s;
}

// Pass 2: exclusive scan of NSEG segment sums (single block, 32/thread)
__global__ void __launch_bounds__(TPB)
k_scan(int* __restrict__ segsums) {
    __shared__ int wsum[4];
    const int lane = threadIdx.x & 63;
    const int wid  = threadIdx.x >> 6;
    int vals[NSEG / TPB];
    const int base = threadIdx.x * (NSEG / TPB);
    int s = 0;
    #pragma unroll
    for (int i = 0; i < NSEG / TPB; i++) { vals[i] = segsums[base + i]; s += vals[i]; }
    int x = s;
    #pragma unroll
    for (int d = 1; d < 64; d <<= 1) {
        int y = __shfl_up(x, d);
        if (lane >= d) x += y;
    }
    if (lane == 63) wsum[wid] = x;
    __syncthreads();
    int wbase = 0;
    #pragma unroll
    for (int w = 0; w < 3; w++) if (w < wid) wbase += wsum[w];
    int ex = wbase + (x - s);
    #pragma unroll
    for (int i = 0; i < NSEG / TPB; i++) { int v = vals[i]; segsums[base + i] = ex; ex += v; }
}

// Per-128-element ballot/popc process step (after loads are in flight)
#define PROC(a, c, uv, ev)                                                    \
    {                                                                         \
        u64 be_on  = __ballot((a).x != 0);                                    \
        u64 bo_on  = __ballot((a).y != 0);                                    \
        u64 be_off = __ballot((c).x != 0);                                    \
        u64 bo_off = __ballot((c).y != 0);                                    \
        const int de = __popcll(be_on & le) - __popcll(be_off & le);          \
        const int pe = basep + de + __popcll(bo_on & lt) - __popcll(bo_off & lt); \
        const int po = basep + de + __popcll(bo_on & le) - __popcll(bo_off & le); \
        basep += __popcll(be_on) - __popcll(be_off)                           \
               + __popcll(bo_on) - __popcll(bo_off);                          \
        const int a0 = pe > 0, a1 = po > 0;                                   \
        cact += a0 + a1;                                                      \
        if (a0 && fabsf((ev).x - (uv).x) > THRESHOLD) cover++;                \
        if (a1 && fabsf((ev).z - (uv).z) > THRESHOLD) cover++;                \
    }

// Pass 3: 4-deep load batches (16 independent loads issued before any
// convergent op), then 4 ballot/popc blocks with static register names.
__global__ void __launch_bounds__(TPB)
k_count(const int2* __restrict__ on2, const int2* __restrict__ off2,
        const float4* __restrict__ u4, const float4* __restrict__ e4,
        const int* __restrict__ segpre, int2* __restrict__ partials) {
    const int lane = threadIdx.x & 63;
    const int wid  = threadIdx.x >> 6;
    const int seg  = blockIdx.x * 4 + wid;
    const int base = seg * (SEG / 2);          // int2 index == float4 index
    const u64 le = (~0ull) >> (63 - lane);     // lanes 0..i
    const u64 lt = le >> 1;                    // lanes 0..i-1

    int basep = segpre[seg];
    int cover = 0, cact = 0;

    #pragma unroll
    for (int g = 0; g < ITERS / 4; ++g) {
        const int i0 = base + g * 256 + lane;
        // ---- 16 independent loads, no convergent ops in between ----
        int2   a0 = on2[i0];        int2   a1 = on2[i0 + 64];
        int2   a2 = on2[i0 + 128];  int2   a3 = on2[i0 + 192];
        int2   c0 = off2[i0];       int2   c1 = off2[i0 + 64];
        int2   c2 = off2[i0 + 128]; int2   c3 = off2[i0 + 192];
        float4 u0 = u4[i0];         float4 u1 = u4[i0 + 64];
        float4 u2 = u4[i0 + 128];   float4 u3 = u4[i0 + 192];
        float4 e0 = e4[i0];         float4 e1 = e4[i0 + 64];
        float4 e2 = e4[i0 + 128];   float4 e3 = e4[i0 + 192];
        // ---- process 4 sub-iterations ----
        PROC(a0, c0, u0, e0);
        PROC(a1, c1, u1, e1);
        PROC(a2, c2, u2, e2);
        PROC(a3, c3, u3, e3);
    }

    #pragma unroll
    for (int d = 32; d > 0; d >>= 1) {
        cover += __shfl_xor(cover, d);
        cact  += __shfl_xor(cact, d);
    }
    __shared__ int sc[4], sa[4];
    if (lane == 0) { sc[wid] = cover; sa[wid] = cact; }
    __syncthreads();
    if (threadIdx.x == 0)
        partials[blockIdx.x] = make_int2(sc[0] + sc[1] + sc[2] + sc[3],
                                         sa[0] + sa[1] + sa[2] + sa[3]);
}

// Pass 4: reduce block partials, divide
__global__ void __launch_bounds__(TPB)
k_final(const int2* __restrict__ partials, float* __restrict__ out) {
    const int lane = threadIdx.x & 63;
    const int wid  = threadIdx.x >> 6;
    int c = 0, a = 0;
    for (int i = threadIdx.x; i < NBLK; i += TPB) {
        int2 p = partials[i];
        c += p.x; a += p.y;
    }
    #pragma unroll
    for (int d = 32; d > 0; d >>= 1) {
        c += __shfl_xor(c, d);
        a += __shfl_xor(a, d);
    }
    __shared__ int sc[4], sa[4];
    if (lane == 0) { sc[wid] = c; sa[wid] = a; }
    __syncthreads();
    if (threadIdx.x == 0) {
        float ctot = (float)(sc[0] + sc[1] + sc[2] + sc[3]);
        float atot = (float)(sa[0] + sa[1] + sa[2] + sa[3]);
        out[0] = ctot / atot;
    }
}

extern "C" void kernel_launch(void* const* d_in, const int* in_sizes, int n_in,
                              void* d_out, int out_size, void* d_ws, size_t ws_size,
                              hipStream_t stream) {
    const float* u   = (const float*)d_in[0];
    const float* e   = (const float*)d_in[1];
    const int*   on  = (const int*)d_in[2];
    const int*   off = (const int*)d_in[3];

    int*  segsums  = (int*)d_ws;                 // NSEG ints (32 KB)
    int2* partials = (int2*)(segsums + NSEG);    // NBLK int2 (16 KB)

    k_segsums<<<NBLK, TPB, 0, stream>>>((const int2*)on, (const int2*)off, segsums);
    k_scan<<<1, TPB, 0, stream>>>(segsums);
    k_count<<<NBLK, TPB, 0, stream>>>((const int2*)on, (const int2*)off,
                                      (const float4*)u, (const float4*)e,
                                      segsums, partials);
    k_final<<<1, TPB, 0, stream>>>(partials, (float*)d_out);
}